// Round 19
// baseline (172.864 us; speedup 1.0000x reference)
//
#include <hip/hip_runtime.h>

#define DDIM 128
#define MSUB 8
#define KCODE 256
#define DSUB 16
#define NLIST 1024
#define NPROBE 32
#define TOPK 100
#define HBINS 4096
#define COLL_CAP 2048
#define RCAP 12
#define SCHUNK 1024

// ==== FROZEN ARITHMETIC (bit-exact vs reference — do not modify) ====

__device__ __forceinline__ float xla_tree16(const float* s) {
  float a[8], b[4], c[2];
  #pragma unroll
  for (int j = 0; j < 8; ++j) a[j] = __fadd_rn(s[j], s[j + 8]);
  #pragma unroll
  for (int j = 0; j < 4; ++j) b[j] = __fadd_rn(a[j], a[j + 4]);
  #pragma unroll
  for (int j = 0; j < 2; ++j) c[j] = __fadd_rn(b[j], b[j + 2]);
  return __fadd_rn(c[0], c[1]);
}

// XLA reduce n=128 from an addressable array (query in LDS)
__device__ __forceinline__ float xla_sumsq128(const float* x) {
  float s[16];
  #pragma unroll
  for (int j = 0; j < 16; ++j) {
    float p0 = __fmul_rn(x[j],       x[j]);
    float p1 = __fmul_rn(x[j + 16],  x[j + 16]);
    float p2 = __fmul_rn(x[j + 32],  x[j + 32]);
    float p3 = __fmul_rn(x[j + 48],  x[j + 48]);
    float p4 = __fmul_rn(x[j + 64],  x[j + 64]);
    float p5 = __fmul_rn(x[j + 80],  x[j + 80]);
    float p6 = __fmul_rn(x[j + 96],  x[j + 96]);
    float p7 = __fmul_rn(x[j + 112], x[j + 112]);
    float r0 = __fadd_rn(p0, p4);
    float r1 = __fadd_rn(p1, p5);
    float r2 = __fadd_rn(p2, p6);
    float r3 = __fadd_rn(p3, p7);
    s[j] = __fadd_rn(__fadd_rn(r0, r1), __fadd_rn(r2, r3));
  }
  return xla_tree16(s);
}

__device__ __forceinline__ float xla_sumsq16(const float* x) {
  float p[16];
  #pragma unroll
  for (int j = 0; j < 16; ++j) p[j] = __fmul_rn(x[j], x[j]);
  float s8[8], s4[4], s2[2];
  #pragma unroll
  for (int j = 0; j < 8; ++j) s8[j] = __fadd_rn(p[j], p[j + 8]);
  #pragma unroll
  for (int j = 0; j < 4; ++j) s4[j] = __fadd_rn(s8[j], s8[j + 4]);
  #pragma unroll
  for (int j = 0; j < 2; ++j) s2[j] = __fadd_rn(s4[j], s4[j + 2]);
  return __fadd_rn(s2[0], s2[1]);
}

__device__ __forceinline__ float chain_dot16(const float* a, const float* b) {
  float dot = 0.f;
  #pragma unroll
  for (int d = 0; d < DSUB; ++d) dot = __fmaf_rn(a[d], b[d], dot);
  return dot;
}

__device__ __forceinline__ float adc_dist(const float* lut, unsigned long long code) {
  float d = lut[(unsigned)(code & 255ULL)];
  d = __fadd_rn(d, lut[256  + (unsigned)((code >> 8)  & 255ULL)]);
  d = __fadd_rn(d, lut[512  + (unsigned)((code >> 16) & 255ULL)]);
  d = __fadd_rn(d, lut[768  + (unsigned)((code >> 24) & 255ULL)]);
  d = __fadd_rn(d, lut[1024 + (unsigned)((code >> 32) & 255ULL)]);
  d = __fadd_rn(d, lut[1280 + (unsigned)((code >> 40) & 255ULL)]);
  d = __fadd_rn(d, lut[1536 + (unsigned)((code >> 48) & 255ULL)]);
  d = __fadd_rn(d, lut[1792 + (unsigned)((code >> 56) & 255ULL)]);
  return d;
}

// ==== helpers ====
__device__ __forceinline__ unsigned block_scan_incl(unsigned v, volatile unsigned* wsum,
                                                    int t, int nwaves) {
  int lane = t & 63, wid = t >> 6;
  #pragma unroll
  for (int off = 1; off < 64; off <<= 1) {
    unsigned u = __shfl_up(v, off, 64);
    if (lane >= off) v += u;
  }
  if (lane == 63) wsum[wid] = v;
  __syncthreads();
  if (wid == 0 && lane < nwaves) {
    unsigned wv = wsum[lane];
    #pragma unroll
    for (int off = 1; off < 16; off <<= 1) {
      unsigned u = __shfl_up(wv, off, 64);
      if (lane >= off) wv += u;
    }
    wsum[lane] = wv;
  }
  __syncthreads();
  return v + (wid > 0 ? wsum[wid - 1] : 0u);
}

// ---------------- fused coarse + LUT + db_list histogram (1024 threads, 2-pass) -------
__global__ __launch_bounds__(1024) void k_coarse_lut(const float* __restrict__ queries,
                                                     const float* __restrict__ centroids,
                                                     const float* __restrict__ codebooks,
                                                     const int* __restrict__ db_list, int N,
                                                     float* __restrict__ lut_g,
                                                     int* __restrict__ probed,
                                                     unsigned* __restrict__ counts) {
  const int qi = blockIdx.x;
  const int t = threadIdx.x;
  __shared__ float qs[DDIM];
  __shared__ unsigned hist[HBINS];
  __shared__ unsigned long long coll[512];
  __shared__ unsigned wsum[16];
  __shared__ unsigned scnt;
  __shared__ int sT32;
  if (t < DDIM) qs[t] = queries[qi * DDIM + t];
  for (int i = t; i < HBINS; i += 1024) hist[i] = 0;
  if (t == 0) { scnt = 0; sT32 = HBINS - 1; }
  __syncthreads();

  // ---- LUT (frozen arithmetic): 2 entries per thread ----
  #pragma unroll
  for (int jj = 0; jj < 2; ++jj) {
    int idx = t + jj * 1024;
    int j = idx >> 8;                 // m in 0..7
    const float* cb = codebooks + (size_t)idx * DSUB;
    const float* qsub = qs + j * DSUB;
    float cbv[DSUB], qv[DSUB];
    #pragma unroll
    for (int d = 0; d < DSUB; ++d) { cbv[d] = cb[d]; qv[d] = qsub[d]; }
    const float qq16 = xla_sumsq16(qv);
    const float cc16 = xla_sumsq16(cbv);
    const float dot16 = chain_dot16(qv, cbv);
    lut_g[(size_t)qi * (MSUB * KCODE) + idx] =
        __fsub_rn(__fadd_rn(qq16, cc16), __fmul_rn(2.0f, dot16));
  }

  // ---- coarse: 1 centroid per thread, two passes (no 128-reg buffer) ----
  const float qq = xla_sumsq128(qs);
  const float* cr = centroids + (size_t)t * DDIM;
  // pass A: dot = single FMA chain, k ascending (frozen)
  float dot = 0.f;
  #pragma unroll
  for (int d = 0; d < DDIM; d += 4) {
    float4 cv = *(const float4*)(cr + d);
    dot = __fmaf_rn(qs[d + 0], cv.x, dot);
    dot = __fmaf_rn(qs[d + 1], cv.y, dot);
    dot = __fmaf_rn(qs[d + 2], cv.z, dot);
    dot = __fmaf_rn(qs[d + 3], cv.w, dot);
  }
  // pass B: cc = xla_sumsq128 arithmetic fed by stride-16 float4 groups (same ops/order)
  float s[16];
  #pragma unroll
  for (int jj = 0; jj < 16; jj += 4) {
    float4 v0 = *(const float4*)(cr + jj);
    float4 v1 = *(const float4*)(cr + jj + 16);
    float4 v2 = *(const float4*)(cr + jj + 32);
    float4 v3 = *(const float4*)(cr + jj + 48);
    float4 v4 = *(const float4*)(cr + jj + 64);
    float4 v5 = *(const float4*)(cr + jj + 80);
    float4 v6 = *(const float4*)(cr + jj + 96);
    float4 v7 = *(const float4*)(cr + jj + 112);
    const float e0[4] = {v0.x, v0.y, v0.z, v0.w};
    const float e1[4] = {v1.x, v1.y, v1.z, v1.w};
    const float e2[4] = {v2.x, v2.y, v2.z, v2.w};
    const float e3[4] = {v3.x, v3.y, v3.z, v3.w};
    const float e4[4] = {v4.x, v4.y, v4.z, v4.w};
    const float e5[4] = {v5.x, v5.y, v5.z, v5.w};
    const float e6[4] = {v6.x, v6.y, v6.z, v6.w};
    const float e7[4] = {v7.x, v7.y, v7.z, v7.w};
    #pragma unroll
    for (int c = 0; c < 4; ++c) {
      float p0 = __fmul_rn(e0[c], e0[c]);
      float p1 = __fmul_rn(e1[c], e1[c]);
      float p2 = __fmul_rn(e2[c], e2[c]);
      float p3 = __fmul_rn(e3[c], e3[c]);
      float p4 = __fmul_rn(e4[c], e4[c]);
      float p5 = __fmul_rn(e5[c], e5[c]);
      float p6 = __fmul_rn(e6[c], e6[c]);
      float p7 = __fmul_rn(e7[c], e7[c]);
      float r0 = __fadd_rn(p0, p4);
      float r1 = __fadd_rn(p1, p5);
      float r2 = __fadd_rn(p2, p6);
      float r3 = __fadd_rn(p3, p7);
      s[jj + c] = __fadd_rn(__fadd_rn(r0, r1), __fadd_rn(r2, r3));
    }
  }
  const float cc = xla_tree16(s);
  float dist = __fsub_rn(__fadd_rn(qq, cc), __fmul_rn(2.0f, dot));
  unsigned bits = __float_as_uint(dist);
  unsigned long long key = ((unsigned long long)bits << 32) | (unsigned)t;
  atomicAdd(&hist[bits >> 19], 1u);
  __syncthreads();

  // threshold bin for rank NPROBE (1024 threads x 4 bins)
  {
    unsigned mysum = 0;
    #pragma unroll
    for (int i = 0; i < 4; ++i) mysum += hist[t * 4 + i];
    unsigned incl = block_scan_incl(mysum, wsum, t, 16);
    unsigned excl = incl - mysum;
    if (excl < NPROBE && NPROBE <= incl) {
      unsigned c2 = excl;
      #pragma unroll
      for (int i = 0; i < 4; ++i) {
        unsigned h = hist[t * 4 + i];
        if (c2 + h >= NPROBE) { sT32 = t * 4 + i; break; }
        c2 += h;
      }
    }
  }
  __syncthreads();
  const int T32 = sT32;
  if ((int)(key >> 51) <= T32) {
    unsigned p = atomicAdd(&scnt, 1u);
    if (p < 512) coll[p] = key;
  }
  __syncthreads();
  unsigned cnt = scnt; if (cnt > 512) cnt = 512;
  for (unsigned i = t; i < cnt; i += 1024) {
    unsigned long long k2 = coll[i];
    unsigned r = 0;
    for (unsigned j = 0; j < cnt; ++j) r += (coll[j] < k2) ? 1u : 0u;
    if (r < NPROBE) probed[qi * NPROBE + r] = (int)(k2 & 0xffffffffULL);
  }
  __syncthreads();

  // ---- fused db_list histogram (reuse hist[0..NLIST-1]) ----
  for (int i = t; i < NLIST; i += 1024) hist[i] = 0;
  __syncthreads();
  for (int n = qi * 1024 + t; n < N; n += 256 * 1024)
    atomicAdd(&hist[db_list[n]], 1u);
  __syncthreads();
  for (int i = t; i < NLIST; i += 1024)
    if (hist[i]) atomicAdd(&counts[i], hist[i]);
}

// ---------------- block-aggregated bucket scatter with local scan ----------------
__global__ __launch_bounds__(256) void k_scatter(const int* __restrict__ db_list,
                                                 const int* __restrict__ db_codes, int N,
                                                 const unsigned* __restrict__ counts,
                                                 unsigned* __restrict__ cursor,
                                                 int4* __restrict__ pack) {
  __shared__ unsigned lhist[NLIST], lbase[NLIST], sbstart[NLIST];
  __shared__ unsigned wsum[16];
  const int t = threadIdx.x;
  const int base = blockIdx.x * SCHUNK;
  {
    unsigned c0 = counts[t * 4], c1 = counts[t * 4 + 1],
             c2 = counts[t * 4 + 2], c3 = counts[t * 4 + 3];
    unsigned sum4 = c0 + c1 + c2 + c3;
    unsigned incl = block_scan_incl(sum4, wsum, t, 4);
    unsigned excl = incl - sum4;
    sbstart[t * 4] = excl;
    sbstart[t * 4 + 1] = excl + c0;
    sbstart[t * 4 + 2] = excl + c0 + c1;
    sbstart[t * 4 + 3] = excl + c0 + c1 + c2;
  }
  for (int i = t; i < NLIST; i += 256) lhist[i] = 0;
  __syncthreads();
  #pragma unroll
  for (int k = 0; k < SCHUNK / 256; ++k) {
    int n = base + k * 256 + t;
    if (n < N) atomicAdd(&lhist[db_list[n]], 1u);
  }
  __syncthreads();
  for (int i = t; i < NLIST; i += 256) {
    unsigned cnt = lhist[i];
    if (cnt) lbase[i] = sbstart[i] + atomicAdd(&cursor[i], cnt);
    lhist[i] = 0;
  }
  __syncthreads();
  #pragma unroll
  for (int k = 0; k < SCHUNK / 256; ++k) {
    int n = base + k * 256 + t;
    if (n < N) {
      int l = db_list[n];
      unsigned pos = lbase[l] + atomicAdd(&lhist[l], 1u);
      const int4* cp = (const int4*)(db_codes + (size_t)n * MSUB);
      int4 c0 = cp[0], c1 = cp[1];
      unsigned lo = (unsigned)(c0.x & 255) | ((unsigned)(c0.y & 255) << 8) |
                    ((unsigned)(c0.z & 255) << 16) | ((unsigned)(c0.w & 255) << 24);
      unsigned hi = (unsigned)(c1.x & 255) | ((unsigned)(c1.y & 255) << 8) |
                    ((unsigned)(c1.z & 255) << 16) | ((unsigned)(c1.w & 255) << 24);
      pack[pos] = make_int4((int)lo, (int)hi, n, 0);
    }
  }
}

// ---------------- main search: contiguous per-thread runs ----------------
__global__ __launch_bounds__(1024, 1) void k_search(const float* __restrict__ lut_g,
                                                    const int* __restrict__ probed,
                                                    const unsigned* __restrict__ counts,
                                                    const int4* __restrict__ pack,
                                                    int* __restrict__ out) {
  const int qi = blockIdx.x;
  const int t = threadIdx.x;
  __shared__ float lut_s[MSUB * KCODE];
  __shared__ unsigned hist[HBINS];
  __shared__ unsigned long long coll[COLL_CAP];
  __shared__ unsigned bst[NLIST + 1];
  __shared__ unsigned pstart[NPROBE], pcum[NPROBE + 1];
  __shared__ unsigned wsum[16];
  __shared__ unsigned scnt;
  __shared__ int sT;

  for (int i = t; i < MSUB * KCODE; i += 1024) lut_s[i] = lut_g[(size_t)qi * (MSUB * KCODE) + i];
  {
    unsigned v = counts[t];
    unsigned incl = block_scan_incl(v, wsum, t, 16);
    bst[t + 1] = incl;
    if (t == 0) bst[0] = 0;
  }
  for (int i = t; i < HBINS; i += 1024) hist[i] = 0;
  if (t == 0) { scnt = 0; sT = HBINS - 1; }
  __syncthreads();
  if (t < NPROBE) {
    int l = probed[qi * NPROBE + t];
    pstart[t] = bst[l];
    pcum[t + 1] = bst[l + 1] - bst[l];
  }
  __syncthreads();
  if (t == 0) {
    unsigned acc = 0;
    pcum[0] = 0;
    for (int j = 1; j <= NPROBE; ++j) { acc += pcum[j]; pcum[j] = acc; }
  }
  __syncthreads();
  const unsigned total = pcum[NPROBE];
  const int C = (int)((total + 1023) >> 10);
  const bool fast = (C <= RCAP);

  unsigned regbits[RCAP], regaddr[RCAP];
  int run = 0;

  if (fast) {
    unsigned g0 = (unsigned)t * C;
    if (g0 < total) {
      unsigned gend = g0 + C; if (gend > total) gend = total;
      run = (int)(gend - g0);
      int lo = 0, hi = NPROBE;
      while (hi - lo > 1) { int mid = (lo + hi) >> 1; if (pcum[mid] <= g0) lo = mid; else hi = mid; }
      unsigned g = g0;
      #pragma unroll
      for (int s = 0; s < RCAP; ++s) {
        if (s < run) {
          while (g >= pcum[lo + 1]) ++lo;
          regaddr[s] = pstart[lo] + (g - pcum[lo]);
          ++g;
        }
      }
    }
    // batched loads + ADC + histogram
    #pragma unroll
    for (int s = 0; s < RCAP; ++s) {
      if (s < run) {
        int4 w = pack[regaddr[s]];
        unsigned long long code = (unsigned)w.x | ((unsigned long long)(unsigned)w.y << 32);
        unsigned bits = __float_as_uint(adc_dist(lut_s, code));
        regbits[s] = bits;
        atomicAdd(&hist[bits >> 19], 1u);
      }
    }
  } else {
    // fallback: strided, no caching
    for (unsigned g = t; g < total; g += 1024) {
      int lo = 0, hi = NPROBE;
      while (hi - lo > 1) { int mid = (lo + hi) >> 1; if (pcum[mid] <= g) lo = mid; else hi = mid; }
      int4 w = pack[pstart[lo] + (g - pcum[lo])];
      unsigned long long code = (unsigned)w.x | ((unsigned long long)(unsigned)w.y << 32);
      atomicAdd(&hist[__float_as_uint(adc_dist(lut_s, code)) >> 19], 1u);
    }
  }
  __syncthreads();

  // find T = bin containing rank TOPK
  {
    unsigned mysum = 0;
    #pragma unroll
    for (int i = 0; i < 4; ++i) mysum += hist[t * 4 + i];
    unsigned incl = block_scan_incl(mysum, wsum, t, 16);
    unsigned excl = incl - mysum;
    if (excl < TOPK && TOPK <= incl) {
      unsigned c = excl;
      #pragma unroll
      for (int i = 0; i < 4; ++i) {
        unsigned h = hist[t * 4 + i];
        if (c + h >= TOPK) { sT = t * 4 + i; break; }
        c += h;
      }
    }
  }
  __syncthreads();
  const int T = sT;

  // pass 2: collect ALL candidates with bin <= T
  if (fast) {
    #pragma unroll
    for (int s = 0; s < RCAP; ++s) {
      if (s < run) {
        unsigned bits = regbits[s];
        if ((int)(bits >> 19) <= T) {
          unsigned n = (unsigned)pack[regaddr[s]].z;
          unsigned p = atomicAdd(&scnt, 1u);
          if (p < COLL_CAP) coll[p] = ((unsigned long long)bits << 32) | n;
        }
      }
    }
  } else {
    for (unsigned g = t; g < total; g += 1024) {
      int lo = 0, hi = NPROBE;
      while (hi - lo > 1) { int mid = (lo + hi) >> 1; if (pcum[mid] <= g) lo = mid; else hi = mid; }
      unsigned addr = pstart[lo] + (g - pcum[lo]);
      int4 w = pack[addr];
      unsigned long long code = (unsigned)w.x | ((unsigned long long)(unsigned)w.y << 32);
      unsigned bits = __float_as_uint(adc_dist(lut_s, code));
      if ((int)(bits >> 19) <= T) {
        unsigned p = atomicAdd(&scnt, 1u);
        if (p < COLL_CAP) coll[p] = ((unsigned long long)bits << 32) | (unsigned)w.z;
      }
    }
  }
  __syncthreads();

  // exact rank by (fp32 bits, index)
  unsigned cnt = scnt;
  if (cnt > COLL_CAP) cnt = COLL_CAP;
  for (unsigned i = t; i < cnt; i += 1024) {
    unsigned long long key = coll[i];
    unsigned r = 0;
    for (unsigned j = 0; j < cnt; ++j) r += (coll[j] < key) ? 1u : 0u;
    if (r < TOPK) out[qi * TOPK + r] = (int)(key & 0xffffffffULL);
  }
}

extern "C" void kernel_launch(void* const* d_in, const int* in_sizes, int n_in,
                              void* d_out, int out_size, void* d_ws, size_t ws_size,
                              hipStream_t stream) {
  const float* queries   = (const float*)d_in[0];
  const float* centroids = (const float*)d_in[1];
  const float* codebooks = (const float*)d_in[2];
  const int*   db_codes  = (const int*)d_in[3];
  const int*   db_list   = (const int*)d_in[4];
  const int N = in_sizes[4];
  const int Q = in_sizes[0] / DDIM;
  int* out = (int*)d_out;

  char* p = (char*)d_ws;
  float* lut_g = (float*)p;        p += (size_t)Q * MSUB * KCODE * 4;
  int* probed_g = (int*)p;         p += (size_t)Q * NPROBE * 4;
  unsigned* counts = (unsigned*)p; p += NLIST * 4;
  unsigned* cursor = (unsigned*)p; p += NLIST * 4;
  int4* pack = (int4*)p;           p += (size_t)N * 16;

  hipMemsetAsync(counts, 0, (size_t)NLIST * 4 * 2, stream); // counts + cursor

  k_coarse_lut<<<Q, 1024, 0, stream>>>(queries, centroids, codebooks, db_list, N,
                                       lut_g, probed_g, counts);
  k_scatter<<<(N + SCHUNK - 1) / SCHUNK, 256, 0, stream>>>(db_list, db_codes, N,
                                                           counts, cursor, pack);
  k_search<<<Q, 1024, 0, stream>>>(lut_g, probed_g, counts, pack, out);
}

// Round 20
// 132.790 us; speedup vs baseline: 1.3018x; 1.3018x over previous
//
#include <hip/hip_runtime.h>

#define DDIM 128
#define MSUB 8
#define KCODE 256
#define DSUB 16
#define NLIST 1024
#define NPROBE 32
#define TOPK 100
#define HBINS 4096
#define COLL_CAP 2048
#define RCAP 10
#define SCHUNK 1024

// ==== FROZEN ARITHMETIC (bit-exact vs reference — do not modify) ====

__device__ __forceinline__ float xla_sumsq128(const float* x) {
  float s[16];
  #pragma unroll
  for (int j = 0; j < 16; ++j) {
    float p0 = __fmul_rn(x[j],       x[j]);
    float p1 = __fmul_rn(x[j + 16],  x[j + 16]);
    float p2 = __fmul_rn(x[j + 32],  x[j + 32]);
    float p3 = __fmul_rn(x[j + 48],  x[j + 48]);
    float p4 = __fmul_rn(x[j + 64],  x[j + 64]);
    float p5 = __fmul_rn(x[j + 80],  x[j + 80]);
    float p6 = __fmul_rn(x[j + 96],  x[j + 96]);
    float p7 = __fmul_rn(x[j + 112], x[j + 112]);
    float r0 = __fadd_rn(p0, p4);
    float r1 = __fadd_rn(p1, p5);
    float r2 = __fadd_rn(p2, p6);
    float r3 = __fadd_rn(p3, p7);
    s[j] = __fadd_rn(__fadd_rn(r0, r1), __fadd_rn(r2, r3));
  }
  float a[8], b[4], c[2];
  #pragma unroll
  for (int j = 0; j < 8; ++j) a[j] = __fadd_rn(s[j], s[j + 8]);
  #pragma unroll
  for (int j = 0; j < 4; ++j) b[j] = __fadd_rn(a[j], a[j + 4]);
  #pragma unroll
  for (int j = 0; j < 2; ++j) c[j] = __fadd_rn(b[j], b[j + 2]);
  return __fadd_rn(c[0], c[1]);
}

__device__ __forceinline__ float xla_sumsq16(const float* x) {
  float p[16];
  #pragma unroll
  for (int j = 0; j < 16; ++j) p[j] = __fmul_rn(x[j], x[j]);
  float s8[8], s4[4], s2[2];
  #pragma unroll
  for (int j = 0; j < 8; ++j) s8[j] = __fadd_rn(p[j], p[j + 8]);
  #pragma unroll
  for (int j = 0; j < 4; ++j) s4[j] = __fadd_rn(s8[j], s8[j + 4]);
  #pragma unroll
  for (int j = 0; j < 2; ++j) s2[j] = __fadd_rn(s4[j], s4[j + 2]);
  return __fadd_rn(s2[0], s2[1]);
}

__device__ __forceinline__ float chain_dot16(const float* a, const float* b) {
  float dot = 0.f;
  #pragma unroll
  for (int d = 0; d < DSUB; ++d) dot = __fmaf_rn(a[d], b[d], dot);
  return dot;
}

__device__ __forceinline__ float adc_dist(const float* lut, unsigned long long code) {
  float d = lut[(unsigned)(code & 255ULL)];
  d = __fadd_rn(d, lut[256  + (unsigned)((code >> 8)  & 255ULL)]);
  d = __fadd_rn(d, lut[512  + (unsigned)((code >> 16) & 255ULL)]);
  d = __fadd_rn(d, lut[768  + (unsigned)((code >> 24) & 255ULL)]);
  d = __fadd_rn(d, lut[1024 + (unsigned)((code >> 32) & 255ULL)]);
  d = __fadd_rn(d, lut[1280 + (unsigned)((code >> 40) & 255ULL)]);
  d = __fadd_rn(d, lut[1536 + (unsigned)((code >> 48) & 255ULL)]);
  d = __fadd_rn(d, lut[1792 + (unsigned)((code >> 56) & 255ULL)]);
  return d;
}

// ==== helpers ====
__device__ __forceinline__ unsigned block_scan_incl(unsigned v, volatile unsigned* wsum,
                                                    int t, int nwaves) {
  int lane = t & 63, wid = t >> 6;
  #pragma unroll
  for (int off = 1; off < 64; off <<= 1) {
    unsigned u = __shfl_up(v, off, 64);
    if (lane >= off) v += u;
  }
  if (lane == 63) wsum[wid] = v;
  __syncthreads();
  if (wid == 0 && lane < nwaves) {
    unsigned wv = wsum[lane];
    #pragma unroll
    for (int off = 1; off < 16; off <<= 1) {
      unsigned u = __shfl_up(wv, off, 64);
      if (lane >= off) wv += u;
    }
    wsum[lane] = wv;
  }
  __syncthreads();
  return v + (wid > 0 ? wsum[wid - 1] : 0u);
}

// ---------------- coarse distances only: Q*4 blocks x 256 threads ----------------
__global__ __launch_bounds__(256) void k_coarse(const float* __restrict__ queries,
                                                const float* __restrict__ centroids,
                                                unsigned long long* __restrict__ keys_g) {
  const int qi = blockIdx.x >> 2;
  const int part = blockIdx.x & 3;
  const int t = threadIdx.x;
  __shared__ float qs[DDIM];
  if (t < DDIM) qs[t] = queries[qi * DDIM + t];
  __syncthreads();
  const float qq = xla_sumsq128(qs);
  const int c = part * 256 + t;
  const float* cr = centroids + (size_t)c * DDIM;
  float cbuf[DDIM];
  #pragma unroll
  for (int d = 0; d < DDIM; d += 4) {
    float4 cv = *(const float4*)(cr + d);
    cbuf[d] = cv.x; cbuf[d + 1] = cv.y; cbuf[d + 2] = cv.z; cbuf[d + 3] = cv.w;
  }
  const float cc = xla_sumsq128(cbuf);
  float dot = 0.f;
  #pragma unroll
  for (int d = 0; d < DDIM; ++d) dot = __fmaf_rn(qs[d], cbuf[d], dot);
  float dist = __fsub_rn(__fadd_rn(qq, cc), __fmul_rn(2.0f, dot));
  unsigned bits = __float_as_uint(dist);
  keys_g[(size_t)qi * NLIST + c] = ((unsigned long long)bits << 32) | (unsigned)c;
}

// ---------------- LUT + db_list histogram: Q blocks x 256 threads ----------------
__global__ __launch_bounds__(256) void k_lut(const float* __restrict__ queries,
                                             const float* __restrict__ codebooks,
                                             const int* __restrict__ db_list, int N,
                                             float* __restrict__ lut_g,
                                             unsigned* __restrict__ counts) {
  const int qi = blockIdx.x;
  const int t = threadIdx.x;
  __shared__ float qs[DDIM];
  __shared__ unsigned hist[NLIST];
  if (t < DDIM) qs[t] = queries[qi * DDIM + t];
  for (int i = t; i < NLIST; i += 256) hist[i] = 0;
  __syncthreads();

  for (int j = 0; j < MSUB; ++j) {
    int idx = j * KCODE + t;
    const float* cb = codebooks + (size_t)idx * DSUB;
    const float* qsub = qs + j * DSUB;
    float cbv[DSUB], qv[DSUB];
    #pragma unroll
    for (int d = 0; d < DSUB; ++d) { cbv[d] = cb[d]; qv[d] = qsub[d]; }
    const float qq16 = xla_sumsq16(qv);
    const float cc16 = xla_sumsq16(cbv);
    const float dot16 = chain_dot16(qv, cbv);
    lut_g[(size_t)qi * (MSUB * KCODE) + idx] =
        __fsub_rn(__fadd_rn(qq16, cc16), __fmul_rn(2.0f, dot16));
  }

  // db_list histogram slice
  for (int n = qi * 256 + t; n < N; n += 256 * 256)
    atomicAdd(&hist[db_list[n]], 1u);
  __syncthreads();
  for (int i = t; i < NLIST; i += 256)
    if (hist[i]) atomicAdd(&counts[i], hist[i]);
}

// ---------------- block-aggregated bucket scatter with local scan ----------------
__global__ __launch_bounds__(256) void k_scatter(const int* __restrict__ db_list,
                                                 const int* __restrict__ db_codes, int N,
                                                 const unsigned* __restrict__ counts,
                                                 unsigned* __restrict__ cursor,
                                                 int4* __restrict__ pack) {
  __shared__ unsigned lhist[NLIST], lbase[NLIST], sbstart[NLIST];
  __shared__ unsigned wsum[16];
  const int t = threadIdx.x;
  const int base = blockIdx.x * SCHUNK;
  {
    unsigned c0 = counts[t * 4], c1 = counts[t * 4 + 1],
             c2 = counts[t * 4 + 2], c3 = counts[t * 4 + 3];
    unsigned sum4 = c0 + c1 + c2 + c3;
    unsigned incl = block_scan_incl(sum4, wsum, t, 4);
    unsigned excl = incl - sum4;
    sbstart[t * 4] = excl;
    sbstart[t * 4 + 1] = excl + c0;
    sbstart[t * 4 + 2] = excl + c0 + c1;
    sbstart[t * 4 + 3] = excl + c0 + c1 + c2;
  }
  for (int i = t; i < NLIST; i += 256) lhist[i] = 0;
  __syncthreads();
  #pragma unroll
  for (int k = 0; k < SCHUNK / 256; ++k) {
    int n = base + k * 256 + t;
    if (n < N) atomicAdd(&lhist[db_list[n]], 1u);
  }
  __syncthreads();
  for (int i = t; i < NLIST; i += 256) {
    unsigned cnt = lhist[i];
    if (cnt) lbase[i] = sbstart[i] + atomicAdd(&cursor[i], cnt);
    lhist[i] = 0;
  }
  __syncthreads();
  #pragma unroll
  for (int k = 0; k < SCHUNK / 256; ++k) {
    int n = base + k * 256 + t;
    if (n < N) {
      int l = db_list[n];
      unsigned pos = lbase[l] + atomicAdd(&lhist[l], 1u);
      const int4* cp = (const int4*)(db_codes + (size_t)n * MSUB);
      int4 c0 = cp[0], c1 = cp[1];
      unsigned lo = (unsigned)(c0.x & 255) | ((unsigned)(c0.y & 255) << 8) |
                    ((unsigned)(c0.z & 255) << 16) | ((unsigned)(c0.w & 255) << 24);
      unsigned hi = (unsigned)(c1.x & 255) | ((unsigned)(c1.y & 255) << 8) |
                    ((unsigned)(c1.z & 255) << 16) | ((unsigned)(c1.w & 255) << 24);
      pack[pos] = make_int4((int)lo, (int)hi, n, 0);
    }
  }
}

// ---------------- main search: inline coarse selection + ADC ----------------
__global__ __launch_bounds__(1024, 1) void k_search(const float* __restrict__ lut_g,
                                                    const unsigned long long* __restrict__ keys_g,
                                                    const unsigned* __restrict__ counts,
                                                    const int4* __restrict__ pack,
                                                    int* __restrict__ out) {
  const int qi = blockIdx.x;
  const int t = threadIdx.x;
  __shared__ float lut_s[MSUB * KCODE];
  __shared__ unsigned hist[HBINS];
  __shared__ unsigned long long coll[COLL_CAP];
  __shared__ unsigned bst[NLIST + 1];
  __shared__ unsigned pstart[NPROBE], pcum[NPROBE + 1];
  __shared__ unsigned wsum[16];
  __shared__ unsigned scnt;
  __shared__ int sT;

  for (int i = t; i < MSUB * KCODE; i += 1024) lut_s[i] = lut_g[(size_t)qi * (MSUB * KCODE) + i];
  const unsigned long long ckey = keys_g[(size_t)qi * NLIST + t];
  for (int i = t; i < HBINS; i += 1024) hist[i] = 0;
  if (t == 0) { scnt = 0; sT = HBINS - 1; }
  // self-scan counts -> bstart (internal syncs also cover hist zeroing)
  {
    unsigned v = counts[t];
    unsigned incl = block_scan_incl(v, wsum, t, 16);
    bst[t + 1] = incl;
    if (t == 0) bst[0] = 0;
  }
  __syncthreads();

  // ---- coarse top-NPROBE selection from ckey ----
  atomicAdd(&hist[(unsigned)(ckey >> 51)], 1u);
  __syncthreads();
  {
    unsigned mysum = 0;
    #pragma unroll
    for (int i = 0; i < 4; ++i) mysum += hist[t * 4 + i];
    unsigned incl = block_scan_incl(mysum, wsum, t, 16);
    unsigned excl = incl - mysum;
    if (excl < NPROBE && NPROBE <= incl) {
      unsigned c2 = excl;
      #pragma unroll
      for (int i = 0; i < 4; ++i) {
        unsigned h = hist[t * 4 + i];
        if (c2 + h >= NPROBE) { sT = t * 4 + i; break; }
        c2 += h;
      }
    }
  }
  __syncthreads();
  {
    const int T32 = sT;
    if ((int)(ckey >> 51) <= T32) {
      unsigned p = atomicAdd(&scnt, 1u);
      if (p < 512) coll[p] = ckey;
    }
  }
  __syncthreads();
  {
    unsigned cnt = scnt; if (cnt > 512) cnt = 512;
    for (unsigned i = t; i < cnt; i += 1024) {
      unsigned long long k2 = coll[i];
      unsigned r = 0;
      for (unsigned j = 0; j < cnt; ++j) r += (coll[j] < k2) ? 1u : 0u;
      if (r < NPROBE) {
        unsigned l = (unsigned)(k2 & 0xffffffffULL);
        pstart[r] = bst[l];
        pcum[r + 1] = bst[l + 1] - bst[l];
      }
    }
  }
  __syncthreads();
  // reset for ADC phase
  for (int i = t; i < HBINS; i += 1024) hist[i] = 0;
  if (t == 0) {
    scnt = 0; sT = HBINS - 1;
    unsigned acc = 0;
    pcum[0] = 0;
    for (int j = 1; j <= NPROBE; ++j) { acc += pcum[j]; pcum[j] = acc; }
  }
  __syncthreads();
  const unsigned total = pcum[NPROBE];

  // pass 1: distances ONCE, bits+addr cached in registers, coarse histogram
  unsigned regbits[RCAP], regaddr[RCAP];
  {
    int s = 0;
    for (unsigned g = t; g < total; g += 1024, ++s) {
      int lo = 0, hi = NPROBE;
      while (hi - lo > 1) { int mid = (lo + hi) >> 1; if (pcum[mid] <= g) lo = mid; else hi = mid; }
      unsigned addr = pstart[lo] + (g - pcum[lo]);
      int4 w = pack[addr];
      unsigned long long code = (unsigned)w.x | ((unsigned long long)(unsigned)w.y << 32);
      unsigned bits = __float_as_uint(adc_dist(lut_s, code));
      if (s < RCAP) { regbits[s] = bits; regaddr[s] = addr; }
      atomicAdd(&hist[bits >> 19], 1u);
    }
  }
  __syncthreads();

  // find T = bin containing rank TOPK
  {
    unsigned mysum = 0;
    #pragma unroll
    for (int i = 0; i < 4; ++i) mysum += hist[t * 4 + i];
    unsigned incl = block_scan_incl(mysum, wsum, t, 16);
    unsigned excl = incl - mysum;
    if (excl < TOPK && TOPK <= incl) {
      unsigned c = excl;
      #pragma unroll
      for (int i = 0; i < 4; ++i) {
        unsigned h = hist[t * 4 + i];
        if (c + h >= TOPK) { sT = t * 4 + i; break; }
        c += h;
      }
    }
  }
  __syncthreads();
  const int T = sT;

  // pass 2: collect ALL candidates with bin <= T (superset of top-TOPK)
  {
    int s = 0;
    for (unsigned g = t; g < total; g += 1024, ++s) {
      unsigned bits, addr;
      if (s < RCAP) { bits = regbits[s]; addr = regaddr[s]; }
      else {
        int l2 = 0, hi = NPROBE;
        while (hi - l2 > 1) { int mid = (l2 + hi) >> 1; if (pcum[mid] <= g) l2 = mid; else hi = mid; }
        addr = pstart[l2] + (g - pcum[l2]);
        int4 w = pack[addr];
        unsigned long long code = (unsigned)w.x | ((unsigned long long)(unsigned)w.y << 32);
        bits = __float_as_uint(adc_dist(lut_s, code));
      }
      if ((int)(bits >> 19) <= T) {
        unsigned n = (unsigned)pack[addr].z;
        unsigned p = atomicAdd(&scnt, 1u);
        if (p < COLL_CAP) coll[p] = ((unsigned long long)bits << 32) | n;
      }
    }
  }
  __syncthreads();

  // exact rank by (fp32 bits, index)
  unsigned cnt = scnt;
  if (cnt > COLL_CAP) cnt = COLL_CAP;
  for (unsigned i = t; i < cnt; i += 1024) {
    unsigned long long key = coll[i];
    unsigned r = 0;
    for (unsigned j = 0; j < cnt; ++j) r += (coll[j] < key) ? 1u : 0u;
    if (r < TOPK) out[qi * TOPK + r] = (int)(key & 0xffffffffULL);
  }
}

extern "C" void kernel_launch(void* const* d_in, const int* in_sizes, int n_in,
                              void* d_out, int out_size, void* d_ws, size_t ws_size,
                              hipStream_t stream) {
  const float* queries   = (const float*)d_in[0];
  const float* centroids = (const float*)d_in[1];
  const float* codebooks = (const float*)d_in[2];
  const int*   db_codes  = (const int*)d_in[3];
  const int*   db_list   = (const int*)d_in[4];
  const int N = in_sizes[4];
  const int Q = in_sizes[0] / DDIM;
  int* out = (int*)d_out;

  char* p = (char*)d_ws;
  float* lut_g = (float*)p;                         p += (size_t)Q * MSUB * KCODE * 4;
  unsigned long long* keys_g = (unsigned long long*)p; p += (size_t)Q * NLIST * 8;
  unsigned* counts = (unsigned*)p;                  p += NLIST * 4;
  unsigned* cursor = (unsigned*)p;                  p += NLIST * 4;
  int4* pack = (int4*)p;                            p += (size_t)N * 16;

  hipMemsetAsync(counts, 0, (size_t)NLIST * 4 * 2, stream); // counts + cursor

  k_coarse<<<Q * 4, 256, 0, stream>>>(queries, centroids, keys_g);
  k_lut<<<Q, 256, 0, stream>>>(queries, codebooks, db_list, N, lut_g, counts);
  k_scatter<<<(N + SCHUNK - 1) / SCHUNK, 256, 0, stream>>>(db_list, db_codes, N,
                                                           counts, cursor, pack);
  k_search<<<Q, 1024, 0, stream>>>(lut_g, keys_g, counts, pack, out);
}